// Round 3
// baseline (121.766 us; speedup 1.0000x reference)
//
#include <hip/hip_runtime.h>

#define D 4096
#define H 512
#define NCH 64
#define CCH 64
#define B 8
#define COUT 8

typedef __bf16 bf16x8 __attribute__((ext_vector_type(8)));
typedef float  f32x4  __attribute__((ext_vector_type(4)));

// workspace layout (float offsets), regions 16B-aligned
#define OFF_P    0                         // P_nh[n][h]           32768
#define OFF_PHN  (OFF_P + NCH*H)           // P_hn[h][n]           32768
#define OFF_UPT  (OFF_PHN + H*NCH)         // up_t[b][h][n]        262144
#define OFF_S    (OFF_UPT + B*H*NCH)       // s[b][h]              4096
#define OFF_ST2  (OFF_S + B*H)             // -2*t*s[b][h]         4096
#define OFF_Q    (OFF_ST2 + B*H)           // q[b][h]              4096
#define OFF_C    (OFF_Q + B*H)             // c[h]                 512
#define OFF_VN   (OFF_C + H)               // ||v_b||+1e-6         64 (pad)
#define OFF_A1   (OFF_VN + 64)             // a1[b][n*64+i]        32768
#define OFF_ZB   (OFF_A1 + B*NCH*CCH)      // zblk[b][i][n*64+k]   2097152
#define OFF_W1H  (OFF_ZB + B*64*4096)      // W1hi bf16 [d][h]     (2M ushort = 1048576 f)
#define OFF_W1L  (OFF_W1H + (D*H)/2)       // W1lo bf16 [d][h]
#define OFF_WH   (OFF_W1L + (D*H)/2)       // whi bf16 [b][n][h]
#define OFF_WL   (OFF_WH + (B*NCH*H)/2)    // wlo bf16 [b][n][h]

__device__ __forceinline__ unsigned short f2bf(float x) {
    unsigned int u = __float_as_uint(x);
    unsigned int r = (u + 0x7FFFu + ((u >> 16) & 1u)) >> 16;   // RNE
    return (unsigned short)r;
}
__device__ __forceinline__ float bf2f(unsigned short s) {
    return __uint_as_float(((unsigned int)s) << 16);
}

// K1: per (n-chunk, h-quarter): float4 over h, j split 8 ways across threads.
// Produces: W1 bf16 hi/lo, P in both layouts, up_t[b][h][n].
__global__ __launch_bounds__(256) void k1_reduce_w1(const float* __restrict__ W1,
                                                    const float* __restrict__ state,
                                                    const float* __restrict__ x0,
                                                    const float* __restrict__ x1,
                                                    const float* __restrict__ tptr,
                                                    float* __restrict__ ws) {
    int n   = blockIdx.x;              // 0..63
    int ht  = blockIdx.y;              // 0..3
    int tid = threadIdx.x;             // 0..255
    int hq  = ht * 32 + (tid & 31);    // float4 group of h: 0..127
    int jh  = tid >> 5;                // 0..7 (j-eighth)

    __shared__ float xs[B][64];
    __shared__ f32x4 red[8][32][9];    // [jh][lane][p,up0..up7]

    float ts = tptr[0];
    float window = 4.f * ts * (1.f - ts);
    if (tid < 64) {
        int d = n * 64 + tid;
        for (int b = 0; b < B; ++b) {
            float a0 = x0[b * D + d];
            float a1v = x1[b * D + d];
            float dev = state[b * D + d];
            xs[b][tid] = a0 + ts * (a1v - a0) + window * dev;
        }
    }
    __syncthreads();

    unsigned short* __restrict__ W1Hp = (unsigned short*)(ws + OFF_W1H);
    unsigned short* __restrict__ W1Lp = (unsigned short*)(ws + OFF_W1L);

    f32x4 p4 = {0.f, 0.f, 0.f, 0.f};
    f32x4 up[B];
#pragma unroll
    for (int b = 0; b < B; ++b) up[b] = p4;

#pragma unroll
    for (int jj = 0; jj < 8; ++jj) {
        int j = jh * 8 + jj;
        int d = n * 64 + j;
        f32x4 w = ((const f32x4*)W1)[d * (H / 4) + hq];
        p4 += w;
#pragma unroll
        for (int b = 0; b < B; ++b) up[b] += w * xs[b][j];
        unsigned short h0 = f2bf(w.x), h1 = f2bf(w.y), h2 = f2bf(w.z), h3 = f2bf(w.w);
        ushort4 hv = {h0, h1, h2, h3};
        ushort4 lv = {f2bf(w.x - bf2f(h0)), f2bf(w.y - bf2f(h1)),
                      f2bf(w.z - bf2f(h2)), f2bf(w.w - bf2f(h3))};
        *(ushort4*)(W1Hp + d * H + hq * 4) = hv;
        *(ushort4*)(W1Lp + d * H + hq * 4) = lv;
    }

    int l = tid & 31;
    red[jh][l][0] = p4;
#pragma unroll
    for (int b = 0; b < B; ++b) red[jh][l][1 + b] = up[b];
    __syncthreads();

    if (jh == 0) {
        f32x4 pt = red[0][l][0];
        f32x4 ut[B];
#pragma unroll
        for (int b = 0; b < B; ++b) ut[b] = red[0][l][1 + b];
        for (int g = 1; g < 8; ++g) {
            pt += red[g][l][0];
#pragma unroll
            for (int b = 0; b < B; ++b) ut[b] += red[g][l][1 + b];
        }
        // P both layouts
        *(f32x4*)(ws + OFF_P + n * H + hq * 4) = pt;
#pragma unroll
        for (int e = 0; e < 4; ++e) ws[OFF_PHN + (hq * 4 + e) * NCH + n] = pt[e];
        // up_t[b][h][n]
#pragma unroll
        for (int b = 0; b < B; ++b)
#pragma unroll
            for (int e = 0; e < 4; ++e)
                ws[OFF_UPT + (b * H + hq * 4 + e) * NCH + n] = ut[b][e];
    }
}

// K2: per-sample: u -> s,st2 ; c ; q ; ||v||  (contiguous f32x4 partial reads)
__global__ void k2_sample(const float* __restrict__ W2,
                          const float* __restrict__ state,
                          float* __restrict__ ws) {
    int b = blockIdx.x, tid = threadIdx.x;     // 8 blocks x 512 threads
    int wid = tid >> 6, lane = tid & 63;
    __shared__ float lm[8][8];
    __shared__ float ms[8];
    __shared__ float lv[8];

    int h = tid;
    f32x4 u4 = {0.f, 0.f, 0.f, 0.f}, c4 = u4;
    const f32x4* upp = (const f32x4*)(ws + OFF_UPT + (b * H + h) * NCH);
    const f32x4* pp  = (const f32x4*)(ws + OFF_PHN + h * NCH);
#pragma unroll
    for (int j = 0; j < 16; ++j) { u4 += upp[j]; c4 += pp[j]; }
    float u = u4.x + u4.y + u4.z + u4.w;
    float c = c4.x + c4.y + c4.z + c4.w;

    float tt  = tanhf(u);
    float s   = 1.f - tt * tt;
    float st2 = -2.f * tt * s;
    ws[OFF_S   + b * H + h] = s;
    ws[OFF_ST2 + b * H + h] = st2;
    ws[OFF_C   + h] = c;   // redundant across blocks — benign

    const float4* w2p = (const float4*)(W2 + h * 8);
    float4 w2a = w2p[0], w2b = w2p[1];
    float w2r[8] = {w2a.x, w2a.y, w2a.z, w2a.w, w2b.x, w2b.y, w2b.z, w2b.w};

    float cs = c * s;
    float pr[8];
#pragma unroll
    for (int o = 0; o < 8; ++o) pr[o] = cs * w2r[o];
#pragma unroll
    for (int mk = 1; mk < 64; mk <<= 1)
#pragma unroll
        for (int o = 0; o < 8; ++o) pr[o] += __shfl_xor(pr[o], mk);
    if (lane == 0)
#pragma unroll
        for (int o = 0; o < 8; ++o) lm[wid][o] = pr[o];

    float v2 = 0.f;
    const float* v = state + (size_t)(B + b) * D;
#pragma unroll
    for (int j = 0; j < D / H; ++j) { float vv = v[j * H + h]; v2 += vv * vv; }
#pragma unroll
    for (int mk = 1; mk < 64; mk <<= 1) v2 += __shfl_xor(v2, mk);
    if (lane == 0) lv[wid] = v2;
    __syncthreads();

    if (tid < 8) {
        float a = 0.f;
        for (int w = 0; w < 8; ++w) a += lm[w][tid];
        ms[tid] = a;
    }
    if (tid == 0) {
        float a = 0.f;
        for (int w = 0; w < 8; ++w) a += lv[w];
        ws[OFF_VN + b] = sqrtf(a) + 1e-6f;
    }
    __syncthreads();

    float q = 0.f;
#pragma unroll
    for (int o = 0; o < 8; ++o) q += w2r[o] * ms[o];
    ws[OFF_Q + b * H + h] = q;
}

// K3: per (n,b): M[o] = sum_h P*s*W2 ; r = W2@M ; w = st2*(P*q + c*r) -> bf16 hi/lo
__global__ void k3_w(const float* __restrict__ W2,
                     float* __restrict__ ws) {
    int n = blockIdx.x, b = blockIdx.y, lane = threadIdx.x;   // 64 threads
    float M[8];
#pragma unroll
    for (int o = 0; o < 8; ++o) M[o] = 0.f;
    for (int j = 0; j < 8; ++j) {
        int h = j * 64 + lane;
        float ps = ws[OFF_P + n * H + h] * ws[OFF_S + b * H + h];
        const float4* wp = (const float4*)(W2 + h * 8);
        float4 wa = wp[0], wb = wp[1];
        M[0] += ps * wa.x; M[1] += ps * wa.y; M[2] += ps * wa.z; M[3] += ps * wa.w;
        M[4] += ps * wb.x; M[5] += ps * wb.y; M[6] += ps * wb.z; M[7] += ps * wb.w;
    }
#pragma unroll
    for (int mk = 1; mk < 64; mk <<= 1)
#pragma unroll
        for (int o = 0; o < 8; ++o) M[o] += __shfl_xor(M[o], mk);

    unsigned short* __restrict__ WHp = (unsigned short*)(ws + OFF_WH);
    unsigned short* __restrict__ WLp = (unsigned short*)(ws + OFF_WL);
    for (int j = 0; j < 8; ++j) {
        int h = j * 64 + lane;
        const float4* wp = (const float4*)(W2 + h * 8);
        float4 wa = wp[0], wb = wp[1];
        float r = wa.x*M[0] + wa.y*M[1] + wa.z*M[2] + wa.w*M[3]
                + wb.x*M[4] + wb.y*M[5] + wb.z*M[6] + wb.w*M[7];
        float P = ws[OFF_P + n * H + h];
        float wv = ws[OFF_ST2 + b * H + h] * (P * ws[OFF_Q + b * H + h] + ws[OFF_C + h] * r);
        unsigned short hi = f2bf(wv);
        WHp[(b * NCH + n) * H + h] = hi;
        WLp[(b * NCH + n) * H + h] = f2bf(wv - bf2f(hi));
    }
}

// K4: per (i, b): G[64n][64k] = w[b] @ W1[i-rows]^T via bf16x3 MFMA, K split over 4 waves.
__global__ __launch_bounds__(256) void k4_mfma(const float* __restrict__ state,
                                               float* __restrict__ ws) {
    int i   = blockIdx.x;   // 0..63
    int b   = blockIdx.y;   // 0..7
    int tid = threadIdx.x;  // 0..255
    int wid = tid >> 6, lane = tid & 63;
    int r16 = lane & 15;
    int kgrp = (lane >> 4) * 8;

    __shared__ float gp[2][64][67];
    __shared__ float coefs[64];

    const unsigned short* __restrict__ W1Hp = (const unsigned short*)(ws + OFF_W1H);
    const unsigned short* __restrict__ W1Lp = (const unsigned short*)(ws + OFF_W1L);
    const unsigned short* __restrict__ WHp  = (const unsigned short*)(ws + OFF_WH);
    const unsigned short* __restrict__ WLp  = (const unsigned short*)(ws + OFF_WL);

    f32x4 acc[4][4];
    f32x4 z4 = {0.f, 0.f, 0.f, 0.f};
#pragma unroll
    for (int m = 0; m < 4; ++m)
#pragma unroll
        for (int c = 0; c < 4; ++c) acc[m][c] = z4;

    int kb = wid * 128 + kgrp;     // wave's K-quarter + lane k-group
#pragma unroll
    for (int ks = 0; ks < 4; ++ks) {
        int k = kb + ks * 32;
        bf16x8 ah[4], al[4], bh[4], bl[4];
#pragma unroll
        for (int m = 0; m < 4; ++m) {
            int off = (b * 64 + m * 16 + r16) * H + k;
            ah[m] = *(const bf16x8*)(WHp + off);
            al[m] = *(const bf16x8*)(WLp + off);
        }
#pragma unroll
        for (int c = 0; c < 4; ++c) {
            int off = (i * 64 + c * 16 + r16) * H + k;
            bh[c] = *(const bf16x8*)(W1Hp + off);
            bl[c] = *(const bf16x8*)(W1Lp + off);
        }
#pragma unroll
        for (int m = 0; m < 4; ++m)
#pragma unroll
            for (int c = 0; c < 4; ++c) {
                acc[m][c] = __builtin_amdgcn_mfma_f32_16x16x32_bf16(ah[m], bh[c], acc[m][c], 0, 0, 0);
                acc[m][c] = __builtin_amdgcn_mfma_f32_16x16x32_bf16(ah[m], bl[c], acc[m][c], 0, 0, 0);
                acc[m][c] = __builtin_amdgcn_mfma_f32_16x16x32_bf16(al[m], bh[c], acc[m][c], 0, 0, 0);
            }
    }

    // cross-wave K reduction
    int rowb = (lane >> 4) * 4;
    if (wid < 2) {
        float (*g)[67] = gp[wid];
#pragma unroll
        for (int m = 0; m < 4; ++m)
#pragma unroll
            for (int c = 0; c < 4; ++c)
#pragma unroll
                for (int e = 0; e < 4; ++e)
                    g[m * 16 + rowb + e][c * 16 + r16] = acc[m][c][e];
    }
    __syncthreads();
    if (wid >= 2) {
        float (*g)[67] = gp[wid - 2];
#pragma unroll
        for (int m = 0; m < 4; ++m)
#pragma unroll
            for (int c = 0; c < 4; ++c)
#pragma unroll
                for (int e = 0; e < 4; ++e)
                    g[m * 16 + rowb + e][c * 16 + r16] += acc[m][c][e];
    }
    __syncthreads();

    const float* v = state + (size_t)(B + b) * D;

    // epilogue A: per-row norm, y, coef (one wave; v read from L2)
    if (tid < 64) {
        int n = tid;
        float ss = 0.f, y = 0.f;
#pragma unroll 8
        for (int k = 0; k < 64; ++k) {
            float g = gp[0][n][k] + gp[1][n][k];
            ss += g * g;
            y  += g * v[n * 64 + k];
        }
        float nrm = sqrtf(ss) + 1e-6f;
        ws[OFF_A1 + (size_t)(b * NCH + n) * CCH + i] = y / nrm;
        coefs[n] = v[n * 64 + i] / nrm;
    }
    __syncthreads();

    // epilogue B: z partial for this i (deterministic, no atomics)
    float* zb = ws + OFF_ZB + ((size_t)b * 64 + i) * 4096;
#pragma unroll
    for (int r = 0; r < 16; ++r) {
        int idx = tid + r * 256;
        int n = idx >> 6, k = idx & 63;
        zb[idx] = (gp[0][n][k] + gp[1][n][k]) * coefs[n];
    }
}

// K5: reduce z partials over i, final assembly
__global__ void k5_final(const float* __restrict__ state,
                         const float* __restrict__ ws,
                         float* __restrict__ out) {
    int idx = blockIdx.x * 256 + threadIdx.x;   // 0..32767
    float vel = state[32768 + idx];
    out[idx] = vel;
    int b = idx >> 12, e = idx & 4095;
    const float* zb = ws + OFF_ZB + (size_t)b * 64 * 4096 + e;
    float z = 0.f;
#pragma unroll 8
    for (int i = 0; i < 64; ++i) z += zb[(size_t)i * 4096];
    float a1 = ws[OFF_A1 + (size_t)b * 4096 + e];
    float av = -0.5f * vel * (a1 + z) / ws[OFF_VN + b];
    out[32768 + idx] = av - 0.1f * state[idx];
}

extern "C" void kernel_launch(void* const* d_in, const int* in_sizes, int n_in,
                              void* d_out, int out_size, void* d_ws, size_t ws_size,
                              hipStream_t stream) {
    const float* t   = (const float*)d_in[0];
    const float* st  = (const float*)d_in[1];
    const float* x0  = (const float*)d_in[2];
    const float* x1  = (const float*)d_in[3];
    const float* W1  = (const float*)d_in[4];
    const float* W2  = (const float*)d_in[5];
    float* out = (float*)d_out;
    float* ws  = (float*)d_ws;

    hipLaunchKernelGGL(k1_reduce_w1, dim3(64, 4), dim3(256), 0, stream, W1, st, x0, x1, t, ws);
    hipLaunchKernelGGL(k2_sample,    dim3(8),     dim3(512), 0, stream, W2, st, ws);
    hipLaunchKernelGGL(k3_w,         dim3(64, 8), dim3(64),  0, stream, W2, ws);
    hipLaunchKernelGGL(k4_mfma,      dim3(64, 8), dim3(256), 0, stream, st, ws);
    hipLaunchKernelGGL(k5_final,     dim3(128),   dim3(256), 0, stream, st, ws, out);
}